// Round 6
// baseline (3449.146 us; speedup 1.0000x reference)
//
#include <hip/hip_runtime.h>
#include <hip/hip_bf16.h>

#define N_NODES 50000
#define N_EDGES 800000
#define D_IN    16
#define D_HID   64
#define D_OUT   16

typedef __hip_bfloat16 bf16;
// may_alias vector type: safe ds_read_b128 from __shared__ float arrays
typedef float v4fa __attribute__((vector_size(16), may_alias));

__device__ __forceinline__ float b2f(bf16 v) { return __bfloat162float(v); }
__device__ __forceinline__ int clampn(int v) {
    return v < 0 ? 0 : (v >= N_NODES ? N_NODES - 1 : v);
}
// dual-dtype scalar read: elem i of a float tensor that is either bf16 or f32
__device__ __forceinline__ float rdf(const void* p, long i, int isbf) {
    return isbf ? b2f(((const bf16*)p)[i]) : ((const float*)p)[i];
}

// ---------------------------------------------------------------------------
// Runtime dtype detection (1 block). flags[0]=1 iff float tensors are bf16.
// flags[1]=1 iff edge_index is int64 words.
// Round-5 evidence: probe selected f32 (finite output) -> inputs are f32,
// but keep the probe as insurance; it is correct for both conventions.
// ---------------------------------------------------------------------------
__global__ void k_detect(const unsigned short* __restrict__ xw,
                         const int* __restrict__ ei, int* __restrict__ flags)
{
    if (threadIdx.x == 0) {
        int inband = 0;
        for (int j = 0; j < 256; j++) {
            unsigned short w = xw[2 * j];
            int e = (w >> 7) & 0xFF;
            if ((w & 0x7FFF) == 0 || (e >= 100 && e <= 140)) inband++;
        }
        flags[0] = (inband >= 192) ? 1 : 0;
        int z = 1;
        for (int j = 1; j < 128; j += 2) z &= (ei[j] == 0) ? 1 : 0;
        flags[1] = z;
    }
}

__global__ __launch_bounds__(256) void k_zero(float* __restrict__ p, int n)
{
    int i = blockIdx.x * 256 + threadIdx.x;
    if (i < n) p[i] = 0.f;
}

// ---------------------------------------------------------------------------
// h = x @ lin_in_w + lin_in_b   (102 MFLOP)
// ---------------------------------------------------------------------------
__global__ __launch_bounds__(256) void k_lin_in(const int* __restrict__ flags,
                                                const void* __restrict__ x,
                                                const void* __restrict__ w,
                                                const void* __restrict__ b,
                                                float* __restrict__ h)
{
    int idx = blockIdx.x * 256 + threadIdx.x;
    if (idx >= N_NODES * D_HID) return;
    const int isbf = flags[0];
    int n = idx >> 6, c = idx & 63;
    float acc = rdf(b, c, isbf);
#pragma unroll
    for (int i = 0; i < D_IN; i++)
        acc += rdf(x, (long)n * D_IN + i, isbf) * rdf(w, (long)i * D_HID + c, isbf);
    h[idx] = acc;
}

// ---------------------------------------------------------------------------
// Per graph-block edge MLP + scatter-add.
// One wave = 4 edges; lane = output channel. Weights staged in LDS as f16
// (rel err 2^-12 -> ~1e-3 on a 0.68-scale output, 10x under threshold).
// Activations in wave-private f32 LDS (strides 136/68: 16B-aligned, 2-way
// banks = free). LDS ~45 KB -> 3 blocks/CU; grid 768 = resident on 256 CUs.
// ---------------------------------------------------------------------------
__global__ __launch_bounds__(256) void k_edge(const int* __restrict__ flags,
                                              const int* __restrict__ ei,
                                              const float* __restrict__ hin,
                                              float* __restrict__ hout,
                                              const void* __restrict__ gw0,
                                              const void* __restrict__ gb0,
                                              const void* __restrict__ gw1,
                                              const void* __restrict__ gb1,
                                              const void* __restrict__ gw2,
                                              const void* __restrict__ gb2,
                                              int kblk)
{
    __shared__ _Float16 sw0[2 * D_HID * D_HID];   // [128][64] 16KB
    __shared__ _Float16 sw1[D_HID * D_HID];       // [64][64]   8KB
    __shared__ _Float16 sw2[D_HID * D_HID];       //            8KB
    __shared__ float sb0[D_HID], sb1[D_HID], sb2[D_HID];
    __shared__ __align__(16) float sin_[4][4 * 136];
    __shared__ __align__(16) float sm1[4][4 * 68];
    __shared__ __align__(16) float sm2[4][4 * 68];

    const int tid  = threadIdx.x;
    const int isbf = flags[0];
    const int is64 = flags[1];

    for (int i = tid; i < 2 * D_HID * D_HID; i += 256)
        sw0[i] = (_Float16)rdf(gw0, (long)kblk * 2 * D_HID * D_HID + i, isbf);
    for (int i = tid; i < D_HID * D_HID; i += 256) {
        sw1[i] = (_Float16)rdf(gw1, (long)kblk * D_HID * D_HID + i, isbf);
        sw2[i] = (_Float16)rdf(gw2, (long)kblk * D_HID * D_HID + i, isbf);
    }
    if (tid < D_HID) {
        sb0[tid] = rdf(gb0, kblk * D_HID + tid, isbf);
        sb1[tid] = rdf(gb1, kblk * D_HID + tid, isbf);
        sb2[tid] = rdf(gb2, kblk * D_HID + tid, isbf);
    }
    __syncthreads();

    const int  strd  = is64 ? 2 : 1;
    const long dbase = is64 ? (long)(2 * N_EDGES) : (long)N_EDGES;

    const int wv = tid >> 6, ln = tid & 63;
    float* xin = sin_[wv];
    float* y1  = sm1[wv];
    float* y2  = sm2[wv];
    const int gwave = blockIdx.x * 4 + wv;
    const int nwave = gridDim.x * 4;

    for (int t4 = gwave; t4 < N_EDGES / 4; t4 += nwave) {
        const int eb = t4 * 4;
        const int s0 = clampn(ei[(long)(eb + 0) * strd]);
        const int s1 = clampn(ei[(long)(eb + 1) * strd]);
        const int s2 = clampn(ei[(long)(eb + 2) * strd]);
        const int s3 = clampn(ei[(long)(eb + 3) * strd]);
        const int d0 = clampn(ei[dbase + (long)(eb + 0) * strd]);
        const int d1 = clampn(ei[dbase + (long)(eb + 1) * strd]);
        const int d2 = clampn(ei[dbase + (long)(eb + 2) * strd]);
        const int d3 = clampn(ei[dbase + (long)(eb + 3) * strd]);

        // stage cat(h[src], h[dst]) for 4 edges; wave-private, program order
        xin[0 * 136 + ln]      = hin[s0 * 64 + ln];
        xin[0 * 136 + 64 + ln] = hin[d0 * 64 + ln];
        xin[1 * 136 + ln]      = hin[s1 * 64 + ln];
        xin[1 * 136 + 64 + ln] = hin[d1 * 64 + ln];
        xin[2 * 136 + ln]      = hin[s2 * 64 + ln];
        xin[2 * 136 + 64 + ln] = hin[d2 * 64 + ln];
        xin[3 * 136 + ln]      = hin[s3 * 64 + ln];
        xin[3 * 136 + 64 + ln] = hin[d3 * 64 + ln];

        // ---- layer 0: [4 x 128] @ [128 x 64], relu ----
        float a0 = sb0[ln], a1 = a0, a2 = a0, a3 = a0;
#pragma unroll 8
        for (int i = 0; i < 2 * D_HID; i += 4) {
            const float wa = (float)sw0[(i + 0) * 64 + ln];
            const float wb = (float)sw0[(i + 1) * 64 + ln];
            const float wc = (float)sw0[(i + 2) * 64 + ln];
            const float wd = (float)sw0[(i + 3) * 64 + ln];
            const v4fa v0 = *(const v4fa*)&xin[0 * 136 + i];
            const v4fa v1 = *(const v4fa*)&xin[1 * 136 + i];
            const v4fa v2 = *(const v4fa*)&xin[2 * 136 + i];
            const v4fa v3 = *(const v4fa*)&xin[3 * 136 + i];
            a0 += v0[0] * wa + v0[1] * wb + v0[2] * wc + v0[3] * wd;
            a1 += v1[0] * wa + v1[1] * wb + v1[2] * wc + v1[3] * wd;
            a2 += v2[0] * wa + v2[1] * wb + v2[2] * wc + v2[3] * wd;
            a3 += v3[0] * wa + v3[1] * wb + v3[2] * wc + v3[3] * wd;
        }
        y1[0 * 68 + ln] = fmaxf(a0, 0.f);
        y1[1 * 68 + ln] = fmaxf(a1, 0.f);
        y1[2 * 68 + ln] = fmaxf(a2, 0.f);
        y1[3 * 68 + ln] = fmaxf(a3, 0.f);

        // ---- layer 1: [4 x 64] @ [64 x 64], relu ----
        a0 = sb1[ln]; a1 = a0; a2 = a0; a3 = a0;
#pragma unroll 8
        for (int i = 0; i < D_HID; i += 4) {
            const float wa = (float)sw1[(i + 0) * 64 + ln];
            const float wb = (float)sw1[(i + 1) * 64 + ln];
            const float wc = (float)sw1[(i + 2) * 64 + ln];
            const float wd = (float)sw1[(i + 3) * 64 + ln];
            const v4fa v0 = *(const v4fa*)&y1[0 * 68 + i];
            const v4fa v1 = *(const v4fa*)&y1[1 * 68 + i];
            const v4fa v2 = *(const v4fa*)&y1[2 * 68 + i];
            const v4fa v3 = *(const v4fa*)&y1[3 * 68 + i];
            a0 += v0[0] * wa + v0[1] * wb + v0[2] * wc + v0[3] * wd;
            a1 += v1[0] * wa + v1[1] * wb + v1[2] * wc + v1[3] * wd;
            a2 += v2[0] * wa + v2[1] * wb + v2[2] * wc + v2[3] * wd;
            a3 += v3[0] * wa + v3[1] * wb + v3[2] * wc + v3[3] * wd;
        }
        y2[0 * 68 + ln] = fmaxf(a0, 0.f);
        y2[1 * 68 + ln] = fmaxf(a1, 0.f);
        y2[2 * 68 + ln] = fmaxf(a2, 0.f);
        y2[3 * 68 + ln] = fmaxf(a3, 0.f);

        // ---- layer 2: [4 x 64] @ [64 x 64], no relu ----
        a0 = sb2[ln]; a1 = a0; a2 = a0; a3 = a0;
#pragma unroll 8
        for (int i = 0; i < D_HID; i += 4) {
            const float wa = (float)sw2[(i + 0) * 64 + ln];
            const float wb = (float)sw2[(i + 1) * 64 + ln];
            const float wc = (float)sw2[(i + 2) * 64 + ln];
            const float wd = (float)sw2[(i + 3) * 64 + ln];
            const v4fa v0 = *(const v4fa*)&y2[0 * 68 + i];
            const v4fa v1 = *(const v4fa*)&y2[1 * 68 + i];
            const v4fa v2 = *(const v4fa*)&y2[2 * 68 + i];
            const v4fa v3 = *(const v4fa*)&y2[3 * 68 + i];
            a0 += v0[0] * wa + v0[1] * wb + v0[2] * wc + v0[3] * wd;
            a1 += v1[0] * wa + v1[1] * wb + v1[2] * wc + v1[3] * wd;
            a2 += v2[0] * wa + v2[1] * wb + v2[2] * wc + v2[3] * wd;
            a3 += v3[0] * wa + v3[1] * wb + v3[2] * wc + v3[3] * wd;
        }

        // ---- scatter-add at dst (64 consecutive floats per wave) ----
        atomicAdd(&hout[d0 * 64 + ln], a0);
        atomicAdd(&hout[d1 * 64 + ln], a1);
        atomicAdd(&hout[d2 * 64 + ln], a2);
        atomicAdd(&hout[d3 * 64 + ln], a3);
    }
}

// ---------------------------------------------------------------------------
// out = h @ lin_out_w + lin_out_b
// OUTPUT IS FLOAT32: reference returns f32 and the harness doc maps
// non-bf16 reference output to float*. (Round-5 bf16 store produced
// error==max|ref| garbage — the checker reads this buffer as f32.)
// ---------------------------------------------------------------------------
__global__ __launch_bounds__(256) void k_lin_out(const int* __restrict__ flags,
                                                 const float* __restrict__ h,
                                                 const void* __restrict__ w,
                                                 const void* __restrict__ b,
                                                 float* __restrict__ out)
{
    int idx = blockIdx.x * 256 + threadIdx.x;
    if (idx >= N_NODES * D_OUT) return;
    const int isbf = flags[0];
    int n = idx >> 4, c = idx & 15;
    float acc = rdf(b, c, isbf);
    const float* hr = h + (long)n * D_HID;
#pragma unroll
    for (int i = 0; i < D_HID; i++) acc += hr[i] * rdf(w, (long)i * D_OUT + c, isbf);
    out[idx] = acc;
}

extern "C" void kernel_launch(void* const* d_in, const int* in_sizes, int n_in,
                              void* d_out, int out_size, void* d_ws, size_t ws_size,
                              hipStream_t stream)
{
    const void* x    = d_in[0];
    // d_in[1] = lframes: unused by the reference
    const int*  ei   = (const int*)d_in[2];
    const void* liw  = d_in[3];
    const void* lib  = d_in[4];
    const void* w0   = d_in[5];
    const void* b0   = d_in[6];
    const void* w1   = d_in[7];
    const void* b1   = d_in[8];
    const void* w2   = d_in[9];
    const void* b2   = d_in[10];
    const void* low  = d_in[11];
    const void* lob  = d_in[12];
    float* out = (float*)d_out;

    // ws layout: [flags: 256B][hA: 12.8MB][hB: 12.8MB] = 25.6MB + 256B
    int*   flags = (int*)d_ws;
    float* hA = (float*)d_ws + 64;
    float* hB = hA + (size_t)N_NODES * D_HID;

    const int HN = N_NODES * D_HID;          // 3.2M floats
    const int gH = (HN + 255) / 256;

    k_detect<<<1, 64, 0, stream>>>((const unsigned short*)x, ei, flags);
    k_lin_in<<<gH, 256, 0, stream>>>(flags, x, liw, lib, hA);

    float* cur = hA;
    float* nxt = hB;
    for (int k = 0; k < 4; k++) {
        k_zero<<<gH, 256, 0, stream>>>(nxt, HN);
        k_edge<<<768, 256, 0, stream>>>(flags, ei, cur, nxt,
                                        w0, b0, w1, b1, w2, b2, k);
        float* t = cur; cur = nxt; nxt = t;
    }

    k_lin_out<<<(N_NODES * D_OUT + 255) / 256, 256, 0, stream>>>(flags, cur, low, lob, out);
}

// Round 8
// 907.058 us; speedup vs baseline: 3.8026x; 3.8026x over previous
//
#include <hip/hip_runtime.h>
#include <hip/hip_bf16.h>

#define N_NODES 50000
#define N_EDGES 800000
#define D_IN    16
#define D_HID   64
#define D_OUT   16

typedef __hip_bfloat16 bf16;
typedef _Float16 f16;
typedef _Float16 f16x8 __attribute__((ext_vector_type(8)));
typedef float    f32x4 __attribute__((ext_vector_type(4)));
// may_alias pointer element types for LDS reinterpret access
typedef _Float16 f16x8a __attribute__((ext_vector_type(8), may_alias));
typedef unsigned u32a   __attribute__((may_alias));

__device__ __forceinline__ float b2f(bf16 v) { return __bfloat162float(v); }
__device__ __forceinline__ int clampn(int v) {
    return v < 0 ? 0 : (v >= N_NODES ? N_NODES - 1 : v);
}
// dual-dtype scalar read (round-6 evidence: inputs are f32; probe kept as insurance)
__device__ __forceinline__ float rdf(const void* p, long i, int isbf) {
    return isbf ? b2f(((const bf16*)p)[i]) : ((const float*)p)[i];
}

__global__ void k_detect(const unsigned short* __restrict__ xw,
                         const int* __restrict__ ei, int* __restrict__ flags)
{
    if (threadIdx.x == 0) {
        int inband = 0;
        for (int j = 0; j < 256; j++) {
            unsigned short w = xw[2 * j];
            int e = (w >> 7) & 0xFF;
            if ((w & 0x7FFF) == 0 || (e >= 100 && e <= 140)) inband++;
        }
        flags[0] = (inband >= 192) ? 1 : 0;
        int z = 1;
        for (int j = 1; j < 128; j += 2) z &= (ei[j] == 0) ? 1 : 0;
        flags[1] = z;
    }
}

__global__ __launch_bounds__(256) void k_zero(float* __restrict__ p, int n)
{
    int i = blockIdx.x * 256 + threadIdx.x;
    if (i < n) p[i] = 0.f;
}

__global__ __launch_bounds__(256) void k_lin_in(const int* __restrict__ flags,
                                                const void* __restrict__ x,
                                                const void* __restrict__ w,
                                                const void* __restrict__ b,
                                                float* __restrict__ h)
{
    int idx = blockIdx.x * 256 + threadIdx.x;
    if (idx >= N_NODES * D_HID) return;
    const int isbf = flags[0];
    int n = idx >> 6, c = idx & 63;
    float acc = rdf(b, c, isbf);
#pragma unroll
    for (int i = 0; i < D_IN; i++)
        acc += rdf(x, (long)n * D_IN + i, isbf) * rdf(w, (long)i * D_HID + c, isbf);
    h[idx] = acc;
}

// ---------------------------------------------------------------------------
// MFMA edge MLP. One wave = 16 edges through all 3 layers.
// mfma_f32_16x16x32_f16:  A[m=lane&15][k=quad*8+j]  B[k=quad*8+j][n=lane&15]
//                         D col=lane&15, row=quad*4+reg   (m89/m120 verified)
// A = edge activations (from LDS, 1 ds_read_b128/chunk), B = weights
// (register-resident: 32 frags = 128 VGPRs, loaded once from transposed LDS).
// Layer transitions: C-layout -> LDS -> A-layout round trip (m120 pattern).
// Strides chosen so every LDS access is <=2-way bank aliased (free, m136)
// and 16B-aligned. LDS total 65,024 B (<=64KB), ~220 VGPR -> 2 blocks/CU.
// ---------------------------------------------------------------------------
#define XIN_ST 136   // halves; [16][136]; 272B rows: bank step 4, 2-way
#define Y_ST    88   // halves; 176B rows: bank step 12 -> quads 2-way
#define W0_ST  136
#define W1_ST   72   // 144B rows: bank step 4, 2-way

__global__ __launch_bounds__(256, 2) void k_edge_mfma(
    const int* __restrict__ flags, const int* __restrict__ eidx,
    const float* __restrict__ hin, float* __restrict__ hout,
    const void* __restrict__ gw0, const void* __restrict__ gb0,
    const void* __restrict__ gw1, const void* __restrict__ gb1,
    const void* __restrict__ gw2, const void* __restrict__ gb2, int kblk)
{
    __shared__ f16 w0T[64 * W0_ST];          // 17408 B
    __shared__ f16 w1T[64 * W1_ST];          //  9216 B
    __shared__ f16 w2T[64 * W1_ST];          //  9216 B
    __shared__ f16 xin_s[4][16 * XIN_ST];    // 17408 B
    __shared__ f16 y_s[4][16 * Y_ST];        // 11264 B
    __shared__ int sidx_s[4][32];            //   512 B

    const int tid  = threadIdx.x;
    const int isbf = flags[0];
    const int is64 = flags[1];

    // ---- stage transposed weights (w?T[n][k]) in f16 ----
    const long wb0 = (long)kblk * 2 * D_HID * D_HID;
    for (int i = tid; i < 2 * D_HID * D_HID; i += 256) {
        int n = i >> 7, k = i & 127;
        w0T[n * W0_ST + k] = (f16)rdf(gw0, wb0 + (long)k * 64 + n, isbf);
    }
    const long wb1 = (long)kblk * D_HID * D_HID;
    for (int i = tid; i < D_HID * D_HID; i += 256) {
        int n = i >> 6, k = i & 63;
        w1T[n * W1_ST + k] = (f16)rdf(gw1, wb1 + (long)k * 64 + n, isbf);
        w2T[n * W1_ST + k] = (f16)rdf(gw2, wb1 + (long)k * 64 + n, isbf);
    }
    __syncthreads();

    const int wv = tid >> 6, ln = tid & 63;
    const int lm = ln & 15, quad = ln >> 4;

    // ---- weight B-frags + biases -> registers (live whole kernel) ----
    f16x8 bw0[4][4], bw1[2][4], bw2[2][4];
#pragma unroll
    for (int c = 0; c < 4; c++)
#pragma unroll
        for (int t = 0; t < 4; t++)
            bw0[c][t] = *(const f16x8a*)&w0T[(t * 16 + lm) * W0_ST + c * 32 + quad * 8];
#pragma unroll
    for (int c = 0; c < 2; c++)
#pragma unroll
        for (int t = 0; t < 4; t++) {
            bw1[c][t] = *(const f16x8a*)&w1T[(t * 16 + lm) * W1_ST + c * 32 + quad * 8];
            bw2[c][t] = *(const f16x8a*)&w2T[(t * 16 + lm) * W1_ST + c * 32 + quad * 8];
        }
    float bias0[4], bias1[4], bias2[4];
#pragma unroll
    for (int t = 0; t < 4; t++) {
        bias0[t] = rdf(gb0, (long)kblk * 64 + t * 16 + lm, isbf);
        bias1[t] = rdf(gb1, (long)kblk * 64 + t * 16 + lm, isbf);
        bias2[t] = rdf(gb2, (long)kblk * 64 + t * 16 + lm, isbf);
    }

    const int  strd  = is64 ? 2 : 1;
    const long dbase = is64 ? (long)(2 * N_EDGES) : (long)N_EDGES;

    f16* xin  = xin_s[wv];
    f16* yb   = y_s[wv];
    int* sidx = sidx_s[wv];
    const int half = ln >> 5, lc = ln & 31;

    const int gwave = blockIdx.x * 4 + wv;
    const int nwave = gridDim.x * 4;

    for (int g = gwave; g < N_EDGES / 16; g += nwave) {
        const int eb = g * 16;
        // edge indices for this 16-edge group (wave-private LDS, program order)
        if (ln < 32) {
            int e = ln & 15;
            long ii = (ln < 16) ? (long)(eb + e) * strd
                                : dbase + (long)(eb + e) * strd;
            sidx[ln] = clampn(eidx[ii]);
        }
        // ---- gather cat(h_src, h_dst) -> xin f16 [16][128] ----
        float2 gv[16];
#pragma unroll
        for (int e = 0; e < 16; e++) {
            int idx = sidx[half * 16 + e];
            gv[e] = *(const float2*)&hin[(long)idx * 64 + lc * 2];
        }
#pragma unroll
        for (int e = 0; e < 16; e++) {
            union { unsigned u; f16 h[2]; } p;
            p.h[0] = (f16)gv[e].x; p.h[1] = (f16)gv[e].y;
            *(u32a*)&xin[e * XIN_ST + lc * 2 + half * 64] = p.u;
        }

        // ---- layer 0: [16x128]@[128x64] + bias, relu ----
        f32x4 acc[4];
#pragma unroll
        for (int t = 0; t < 4; t++)
            acc[t] = (f32x4){bias0[t], bias0[t], bias0[t], bias0[t]};
#pragma unroll
        for (int c = 0; c < 4; c++) {
            f16x8 a = *(const f16x8a*)&xin[lm * XIN_ST + c * 32 + quad * 8];
#pragma unroll
            for (int t = 0; t < 4; t++)
                acc[t] = __builtin_amdgcn_mfma_f32_16x16x32_f16(a, bw0[c][t], acc[t], 0, 0, 0);
        }
#pragma unroll
        for (int t = 0; t < 4; t++)
#pragma unroll
            for (int r = 0; r < 4; r++)
                yb[(quad * 4 + r) * Y_ST + t * 16 + lm] = (f16)fmaxf(acc[t][r], 0.f);

        // ---- layer 1: [16x64]@[64x64] + bias, relu ----
#pragma unroll
        for (int t = 0; t < 4; t++)
            acc[t] = (f32x4){bias1[t], bias1[t], bias1[t], bias1[t]};
#pragma unroll
        for (int c = 0; c < 2; c++) {
            f16x8 a = *(const f16x8a*)&yb[lm * Y_ST + c * 32 + quad * 8];
#pragma unroll
            for (int t = 0; t < 4; t++)
                acc[t] = __builtin_amdgcn_mfma_f32_16x16x32_f16(a, bw1[c][t], acc[t], 0, 0, 0);
        }
#pragma unroll
        for (int t = 0; t < 4; t++)
#pragma unroll
            for (int r = 0; r < 4; r++)
                yb[(quad * 4 + r) * Y_ST + t * 16 + lm] = (f16)fmaxf(acc[t][r], 0.f);

        // ---- layer 2: [16x64]@[64x64] + bias (no relu) ----
#pragma unroll
        for (int t = 0; t < 4; t++)
            acc[t] = (f32x4){bias2[t], bias2[t], bias2[t], bias2[t]};
#pragma unroll
        for (int c = 0; c < 2; c++) {
            f16x8 a = *(const f16x8a*)&yb[lm * Y_ST + c * 32 + quad * 8];
#pragma unroll
            for (int t = 0; t < 4; t++)
                acc[t] = __builtin_amdgcn_mfma_f32_16x16x32_f16(a, bw2[c][t], acc[t], 0, 0, 0);
        }

        // ---- scatter-add (C-layout: row=edge=quad*4+r, col=t*16+lm) ----
        int drow[4];
#pragma unroll
        for (int r = 0; r < 4; r++) drow[r] = sidx[16 + quad * 4 + r];
#pragma unroll
        for (int t = 0; t < 4; t++)
#pragma unroll
            for (int r = 0; r < 4; r++)
                atomicAdd(&hout[(long)drow[r] * 64 + t * 16 + lm], acc[t][r]);
    }
}

__global__ __launch_bounds__(256) void k_lin_out(const int* __restrict__ flags,
                                                 const float* __restrict__ h,
                                                 const void* __restrict__ w,
                                                 const void* __restrict__ b,
                                                 float* __restrict__ out)
{
    int idx = blockIdx.x * 256 + threadIdx.x;
    if (idx >= N_NODES * D_OUT) return;
    const int isbf = flags[0];
    int n = idx >> 4, c = idx & 15;
    float acc = rdf(b, c, isbf);
    const float* hr = h + (long)n * D_HID;
#pragma unroll
    for (int i = 0; i < D_HID; i++) acc += hr[i] * rdf(w, (long)i * D_OUT + c, isbf);
    out[idx] = acc;
}

extern "C" void kernel_launch(void* const* d_in, const int* in_sizes, int n_in,
                              void* d_out, int out_size, void* d_ws, size_t ws_size,
                              hipStream_t stream)
{
    const void* x    = d_in[0];
    // d_in[1] = lframes: unused by the reference
    const int*  ei   = (const int*)d_in[2];
    const void* liw  = d_in[3];
    const void* lib  = d_in[4];
    const void* w0   = d_in[5];
    const void* b0   = d_in[6];
    const void* w1   = d_in[7];
    const void* b1   = d_in[8];
    const void* w2   = d_in[9];
    const void* b2   = d_in[10];
    const void* low  = d_in[11];
    const void* lob  = d_in[12];
    float* out = (float*)d_out;

    // ws layout: [flags: 256B][hA: 12.8MB][hB: 12.8MB]
    int*   flags = (int*)d_ws;
    float* hA = (float*)d_ws + 64;
    float* hB = hA + (size_t)N_NODES * D_HID;

    const int HN = N_NODES * D_HID;
    const int gH = (HN + 255) / 256;

    k_detect<<<1, 64, 0, stream>>>((const unsigned short*)x, ei, flags);
    k_lin_in<<<gH, 256, 0, stream>>>(flags, x, liw, lib, hA);

    float* cur = hA;
    float* nxt = hB;
    for (int k = 0; k < 4; k++) {
        k_zero<<<gH, 256, 0, stream>>>(nxt, HN);
        // 512 blocks = 2 blocks/CU (VGPR/LDS-matched residency)
        k_edge_mfma<<<512, 256, 0, stream>>>(flags, ei, cur, nxt,
                                             w0, b0, w1, b1, w2, b2, k);
        float* t = cur; cur = nxt; nxt = t;
    }

    k_lin_out<<<(N_NODES * D_OUT + 255) / 256, 256, 0, stream>>>(flags, cur, low, lob, out);
}